// Round 1
// baseline (4843.177 us; speedup 1.0000x reference)
//
#include <hip/hip_runtime.h>

// ICON-LM transformer forward, bf16 MFMA pipeline.
// B=16 L=750 D=1024 H=16 HD=64 NL=6 DFF=4096. Residual stream fp32, GEMMs bf16.

#define Bz  16
#define Lz  750
#define Dz  1024
#define Hz  16
#define HDz 64
#define NLz 6
#define DFFz 4096
#define Mz  (Bz*Lz)          // 12000
#define NEGB (-1e9f)
#define QKVPART ((size_t)Bz*Hz*Lz*HDz)   // 12,288,000 elems per q/k/v part

typedef unsigned short u16;
typedef unsigned int   u32;
typedef __attribute__((ext_vector_type(8))) short bf8;    // 8 bf16 (4 VGPRs)
typedef __attribute__((ext_vector_type(4))) float f4;
typedef __attribute__((ext_vector_type(4))) unsigned short u16x4;
typedef __attribute__((ext_vector_type(4))) int i4;

__device__ __forceinline__ u16 f2b(float f){
  u32 u = __builtin_bit_cast(u32, f);
  u += 0x7fffu + ((u >> 16) & 1u);          // RNE
  return (u16)(u >> 16);
}
__device__ __forceinline__ float b2f(u16 h){
  u32 u = ((u32)h) << 16;
  return __builtin_bit_cast(float, u);
}
__device__ __forceinline__ void glds16(const void* g, void* l){
  __builtin_amdgcn_global_load_lds((const __attribute__((address_space(1))) void*)g,
                                   (__attribute__((address_space(3))) void*)l, 16, 0, 0);
}

// analytic mask: types per demo-group of 150 = 50 cond(0) + 50 qoi-q(1) + 50 qoi-v(2)
__device__ __forceinline__ float bias_qk(int qi, int kj){
  const int gq = qi / 150, rq = qi - gq*150;
  const int gk = kj / 150, rk = kj - gk*150;
  const int tq = rq < 50 ? 0 : (rq < 100 ? 1 : 2);
  const int tk = rk < 50 ? 0 : (rk < 100 ? 1 : 2);
  const bool prev = (gk < gq) && (tk < 2);
  const bool same = (gk == gq) && ((tk == 0) || (tq == 1 && tk == 1) || (tq == 2 && qi == kj));
  return (prev || same) ? 0.f : NEGB;
}

// ---------------- embed: x = seq @ pre_W + pre_b + pe[pos] ----------------
__global__ __launch_bounds__(256) void k_embed(const float* __restrict__ seq,
    const float* __restrict__ preW, const float* __restrict__ preb,
    const float* __restrict__ pe, float* __restrict__ x, u16* __restrict__ xb){
  const int m = blockIdx.x, t = threadIdx.x;
  const int l = m % Lz;
  const int r = l % 150;
  const int p = r < 50 ? r : (r < 100 ? r - 50 : r - 100);
  const float s0 = seq[m*5+0], s1 = seq[m*5+1], s2 = seq[m*5+2],
              s3 = seq[m*5+3], s4 = seq[m*5+4];
  const int d = t*4;
  f4 acc = *(const f4*)&preb[d];
  acc += *(const f4*)&pe[p*Dz + d];
  acc += s0 * *(const f4*)&preW[0*Dz + d];
  acc += s1 * *(const f4*)&preW[1*Dz + d];
  acc += s2 * *(const f4*)&preW[2*Dz + d];
  acc += s3 * *(const f4*)&preW[3*Dz + d];
  acc += s4 * *(const f4*)&preW[4*Dz + d];
  *(f4*)&x[(size_t)m*Dz + d] = acc;
  u16x4 hv = { f2b(acc.x), f2b(acc.y), f2b(acc.z), f2b(acc.w) };
  *(u16x4*)&xb[(size_t)m*Dz + d] = hv;
}

// ---------------- weight transpose+convert: W(KxN f32) -> Wt(NxK bf16) ----------------
__global__ __launch_bounds__(256) void k_transpose(const float* __restrict__ W,
    u16* __restrict__ Wt, int K, int N){
  __shared__ float tile[32][33];
  const int tx = threadIdx.x, ty = threadIdx.y;
  const int n0 = blockIdx.x*32, k0 = blockIdx.y*32;
  #pragma unroll
  for (int i = 0; i < 4; i++){
    const int k = ty + i*8;
    tile[k][tx] = W[(size_t)(k0+k)*N + n0+tx];
  }
  __syncthreads();
  #pragma unroll
  for (int i = 0; i < 4; i++){
    const int n = ty + i*8;
    Wt[(size_t)(n0+n)*K + k0+tx] = f2b(tile[tx][n]);
  }
}

// ---------------- GEMM (TN): C[M,N] = A[M,K](bf16) @ Bt[N,K]^T (bf16) + bias ----------------
// EPI 0: split-scatter qkv head-major bf16; EPI 1: x(fp32) += C; EPI 2: h = bf16(gelu(C))
template<int EPI>
__global__ __launch_bounds__(256, 2) void k_gemm(
    const u16* __restrict__ A, const u16* __restrict__ Bt,
    int M, int N, int K,
    const float* __restrict__ bias,
    float* __restrict__ xres, u16* __restrict__ outb){
  __shared__ u16 As[128*64];
  __shared__ u16 Bs[128*64];
  const int t = threadIdx.x;
  const int m0 = blockIdx.x*128, n0 = blockIdx.y*128;
  const int w = t >> 6, lane = t & 63;
  const int wm = (w >> 1)*64, wn = (w & 1)*64;
  const int cl = lane & 15, g4 = lane >> 4;
  f4 acc[4][4] = {};
  const int srow = t >> 3, scol = (t & 7)*8;
  const int lds_off = srow*64 + scol;
  for (int k0 = 0; k0 < K; k0 += 64){
    #pragma unroll
    for (int c = 0; c < 4; c++){
      int ra = m0 + c*32 + srow; ra = ra < M ? ra : M-1;
      glds16(A + (size_t)ra*K + k0 + scol, &As[c*2048 + lds_off]);
      const int rb = n0 + c*32 + srow;
      glds16(Bt + (size_t)rb*K + k0 + scol, &Bs[c*2048 + lds_off]);
    }
    __syncthreads();
    #pragma unroll
    for (int kk = 0; kk < 2; kk++){
      const int ko = kk*32 + g4*8;
      bf8 af[4], bfr[4];
      #pragma unroll
      for (int i = 0; i < 4; i++) af[i]  = *(const bf8*)&As[(wm + i*16 + cl)*64 + ko];
      #pragma unroll
      for (int j = 0; j < 4; j++) bfr[j] = *(const bf8*)&Bs[(wn + j*16 + cl)*64 + ko];
      #pragma unroll
      for (int i = 0; i < 4; i++)
        #pragma unroll
        for (int j = 0; j < 4; j++)
          acc[i][j] = __builtin_amdgcn_mfma_f32_16x16x32_bf16(af[i], bfr[j], acc[i][j], 0, 0, 0);
    }
    __syncthreads();
  }
  // epilogue: C row m = m0+wm+i*16+g4*4+r ; col n = n0+wn+j*16+cl
  const int rl = g4*4;
  #pragma unroll
  for (int i = 0; i < 4; i++){
    #pragma unroll
    for (int j = 0; j < 4; j++){
      const int gn = n0 + wn + j*16 + cl;
      const float bsv = bias[gn];
      #pragma unroll
      for (int r = 0; r < 4; r++){
        const int gm = m0 + wm + i*16 + rl + r;
        if (gm < M){
          const float v = acc[i][j][r] + bsv;
          if constexpr (EPI == 1){
            xres[(size_t)gm*N + gn] += v;
          } else if constexpr (EPI == 2){
            const float ge = 0.5f*v*(1.0f + erff(v*0.70710678f));
            outb[(size_t)gm*N + gn] = f2b(ge);
          } else {
            const int part = gn >> 10;
            const int hh = (gn >> 6) & 15;
            const int dd = gn & 63;
            const int b = gm / Lz, lr = gm - b*Lz;
            outb[(size_t)part*QKVPART + ((size_t)(b*Hz + hh)*Lz + lr)*HDz + dd] = f2b(v);
          }
        }
      }
    }
  }
}

// ---------------- fused attention (flash-style, online softmax) ----------------
// grid (6 q-tiles, 256 bh). 4 waves x 32 q-rows. K/V tiles of 64 keys.
__global__ __launch_bounds__(256) void k_attn(const u16* __restrict__ qb,
    const u16* __restrict__ kb, const u16* __restrict__ vb, u16* __restrict__ ob){
  __shared__ u16 Ks[64*64];
  __shared__ u16 Vt[64*72];        // transposed: [d][key], padded
  __shared__ u16 Ps[4][32*72];     // per-wave P, padded
  const int t = threadIdx.x, w = t >> 6, lane = t & 63;
  const int cl = lane & 15, g4 = lane >> 4;
  const int bh = blockIdx.y, b = bh >> 4, h = bh & 15;
  const int q0 = blockIdx.x*128 + w*32;
  const u16* qhp = qb + (size_t)bh*(Lz*HDz);
  const u16* khp = kb + (size_t)bh*(Lz*HDz);
  const u16* vhp = vb + (size_t)bh*(Lz*HDz);
  bf8 qf[2][2];
  #pragma unroll
  for (int i = 0; i < 2; i++){
    int qr = q0 + i*16 + cl; if (qr > Lz-1) qr = Lz-1;
    #pragma unroll
    for (int kk = 0; kk < 2; kk++)
      qf[i][kk] = *(const bf8*)&qhp[(size_t)qr*HDz + kk*32 + g4*8];
  }
  f4 oacc[2][4] = {};
  float mrun[2][4], lrun[2][4];
  #pragma unroll
  for (int i = 0; i < 2; i++)
    #pragma unroll
    for (int r = 0; r < 4; r++){ mrun[i][r] = -1e30f; lrun[i][r] = 0.f; }
  const f4 z4 = {0.f, 0.f, 0.f, 0.f};
  for (int kt = 0; kt < 12; kt++){
    const int kstart = kt*64;
    #pragma unroll
    for (int c = 0; c < 2; c++)
      glds16(khp + (size_t)kstart*HDz + c*2048 + t*8, &Ks[c*2048 + t*8]);
    #pragma unroll
    for (int c = 0; c < 2; c++){
      const int idx = c*2048 + t*8;
      const int key = idx >> 6, d0 = idx & 63;
      union { i4 v; u16 u[8]; } raw;
      raw.v = *(const i4*)&vhp[(size_t)kstart*HDz + idx];
      #pragma unroll
      for (int e = 0; e < 8; e++) Vt[(d0+e)*72 + key] = raw.u[e];
    }
    __syncthreads();
    // QK^T : S[q(32) x key(64)] per wave
    f4 sacc[2][4];
    #pragma unroll
    for (int kk = 0; kk < 2; kk++){
      const int ko = kk*32 + g4*8;
      bf8 kf[4];
      #pragma unroll
      for (int nf = 0; nf < 4; nf++) kf[nf] = *(const bf8*)&Ks[(nf*16 + cl)*64 + ko];
      #pragma unroll
      for (int i = 0; i < 2; i++)
        #pragma unroll
        for (int nf = 0; nf < 4; nf++)
          sacc[i][nf] = __builtin_amdgcn_mfma_f32_16x16x32_bf16(qf[i][kk], kf[nf],
                          kk == 0 ? z4 : sacc[i][nf], 0, 0, 0);
    }
    // online softmax; lane owns rows g4*4+r of each 16-row frag, col = key nf*16+cl
    #pragma unroll
    for (int i = 0; i < 2; i++){
      #pragma unroll
      for (int r = 0; r < 4; r++){
        const int gqr = q0 + i*16 + g4*4 + r;
        float sv[4];
        #pragma unroll
        for (int nf = 0; nf < 4; nf++){
          const int gk = kstart + nf*16 + cl;
          float bv = NEGB;
          if (gk < Lz && gqr < Lz) bv = bias_qk(gqr, gk);
          sv[nf] = sacc[i][nf][r]*0.125f + bv;
        }
        float tm = fmaxf(fmaxf(sv[0], sv[1]), fmaxf(sv[2], sv[3]));
        #pragma unroll
        for (int off = 1; off < 16; off <<= 1) tm = fmaxf(tm, __shfl_xor(tm, off));
        const float mnew = fmaxf(mrun[i][r], tm);
        const float sc = __expf(mrun[i][r] - mnew);
        float ps = 0.f;
        u16 pbv[4];
        #pragma unroll
        for (int nf = 0; nf < 4; nf++){
          const float p = __expf(sv[nf] - mnew);
          ps += p;
          pbv[nf] = f2b(p);
        }
        #pragma unroll
        for (int off = 1; off < 16; off <<= 1) ps += __shfl_xor(ps, off);
        lrun[i][r] = lrun[i][r]*sc + ps;
        mrun[i][r] = mnew;
        #pragma unroll
        for (int nf = 0; nf < 4; nf++){
          oacc[i][nf][r] *= sc;
          Ps[w][(i*16 + g4*4 + r)*72 + nf*16 + cl] = pbv[nf];
        }
      }
    }
    // PV : O += P @ V  (P from LDS in A-layout, V from transposed tile)
    #pragma unroll
    for (int kk = 0; kk < 2; kk++){
      const int ko = kk*32 + g4*8;
      bf8 pa[2], vf[4];
      #pragma unroll
      for (int i = 0; i < 2; i++) pa[i] = *(const bf8*)&Ps[w][(i*16 + cl)*72 + ko];
      #pragma unroll
      for (int nf = 0; nf < 4; nf++) vf[nf] = *(const bf8*)&Vt[(nf*16 + cl)*72 + ko];
      #pragma unroll
      for (int i = 0; i < 2; i++)
        #pragma unroll
        for (int nf = 0; nf < 4; nf++)
          oacc[i][nf] = __builtin_amdgcn_mfma_f32_16x16x32_bf16(pa[i], vf[nf], oacc[i][nf], 0, 0, 0);
    }
    __syncthreads();
  }
  #pragma unroll
  for (int i = 0; i < 2; i++)
    #pragma unroll
    for (int r = 0; r < 4; r++){
      const int gqr = q0 + i*16 + g4*4 + r;
      if (gqr < Lz){
        const float inv = 1.f / lrun[i][r];
        #pragma unroll
        for (int nf = 0; nf < 4; nf++)
          ob[((size_t)b*Lz + gqr)*Dz + h*HDz + nf*16 + cl] = f2b(oacc[i][nf][r]*inv);
      }
    }
}

// ---------------- layernorm (in-place on fp32 x; also refresh bf16 xb) ----------------
__global__ __launch_bounds__(256) void k_ln(float* __restrict__ x, u16* __restrict__ xb,
    const float* __restrict__ g, const float* __restrict__ bb){
  const int m = blockIdx.x, t = threadIdx.x;
  float* xr = x + (size_t)m*Dz;
  f4 v = *(const f4*)&xr[t*4];
  float s = v.x + v.y + v.z + v.w;
  float q = v.x*v.x + v.y*v.y + v.z*v.z + v.w*v.w;
  #pragma unroll
  for (int off = 1; off < 64; off <<= 1){
    s += __shfl_xor(s, off);
    q += __shfl_xor(q, off);
  }
  __shared__ float ss[4], sq[4];
  const int w = t >> 6;
  if ((t & 63) == 0){ ss[w] = s; sq[w] = q; }
  __syncthreads();
  s = ss[0] + ss[1] + ss[2] + ss[3];
  q = sq[0] + sq[1] + sq[2] + sq[3];
  const float mean = s * (1.f/1024.f);
  const float var  = q * (1.f/1024.f) - mean*mean;
  const float rs = rsqrtf(var + 1e-5f);
  const f4 gg = *(const f4*)&g[t*4];
  const f4 bv = *(const f4*)&bb[t*4];
  f4 o;
  o.x = (v.x - mean)*rs*gg.x + bv.x;
  o.y = (v.y - mean)*rs*gg.y + bv.y;
  o.z = (v.z - mean)*rs*gg.z + bv.z;
  o.w = (v.w - mean)*rs*gg.w + bv.w;
  *(f4*)&xr[t*4] = o;
  u16x4 hv = { f2b(o.x), f2b(o.y), f2b(o.z), f2b(o.w) };
  *(u16x4*)&xb[(size_t)m*Dz + t*4] = hv;
}

// ---------------- final projection + gather ----------------
__global__ __launch_bounds__(64) void k_out(const float* __restrict__ x,
    const float* __restrict__ pw, const float* __restrict__ pb, float* __restrict__ out){
  const int bid = blockIdx.x, lane = threadIdx.x;   // bid = b*250 + dd*50 + qq
  const int b = bid / 250, oi = bid - b*250;
  const int dd = oi / 50, qq = oi - dd*50;
  const int l = dd*150 + 100 + qq;
  const float* xr = x + ((size_t)b*Lz + l)*Dz;
  float a0 = 0.f, a1 = 0.f;
  #pragma unroll
  for (int c = 0; c < 4; c++){
    const int d = c*256 + lane*4;
    const f4 v  = *(const f4*)&xr[d];
    const f4 p0 = *(const f4*)&pw[2*d];
    const f4 p1 = *(const f4*)&pw[2*d + 4];
    a0 += v.x*p0.x + v.y*p0.z + v.z*p1.x + v.w*p1.z;
    a1 += v.x*p0.y + v.y*p0.w + v.z*p1.y + v.w*p1.w;
  }
  #pragma unroll
  for (int off = 32; off > 0; off >>= 1){
    a0 += __shfl_xor(a0, off);
    a1 += __shfl_xor(a1, off);
  }
  if (lane == 0){
    out[(size_t)bid*2 + 0] = a0 + pb[0];
    out[(size_t)bid*2 + 1] = a1 + pb[1];
  }
}

extern "C" void kernel_launch(void* const* d_in, const int* in_sizes, int n_in,
                              void* d_out, int out_size, void* d_ws, size_t ws_size,
                              hipStream_t stream){
  (void)in_sizes; (void)n_in; (void)out_size; (void)ws_size;
  const float* seq   = (const float*)d_in[0];
  const float* preW  = (const float*)d_in[1];
  const float* preb  = (const float*)d_in[2];
  const float* pe    = (const float*)d_in[3];
  const float* Wqkv  = (const float*)d_in[4];
  const float* bqkv  = (const float*)d_in[5];
  const float* Wo    = (const float*)d_in[6];
  const float* bo    = (const float*)d_in[7];
  const float* ln1g  = (const float*)d_in[8];
  const float* ln1b  = (const float*)d_in[9];
  const float* ln2g  = (const float*)d_in[10];
  const float* ln2b  = (const float*)d_in[11];
  const float* W1    = (const float*)d_in[12];
  const float* b1    = (const float*)d_in[13];
  const float* W2    = (const float*)d_in[14];
  const float* b2    = (const float*)d_in[15];
  const float* postW = (const float*)d_in[16];
  const float* postb = (const float*)d_in[17];
  float* out = (float*)d_out;

  char* ws = (char*)d_ws;
  float* x  = (float*)(ws + 0);            // 12000*1024 f32  = 49,152,000 B
  u16*   xb = (u16*)(ws + 49152000);       // 12000*1024 bf16 = 24,576,000 B
  u16*   R  = (u16*)(ws + 73728000);       // union region, 98,304,000 B
  u16*   wt = (u16*)(ws + 172032000);      // transposed weights, 8,388,608 B
  u16* qB = R;
  u16* kB = R + QKVPART;
  u16* vB = R + 2*QKVPART;
  u16* oB = R + 3*QKVPART;
  u16* hB = R;                              // FFN hidden aliases qkv+o region

  k_embed<<<Mz, 256, 0, stream>>>(seq, preW, preb, pe, x, xb);
  const dim3 tb(32, 8);
  for (int l = 0; l < NLz; l++){
    // QKV
    k_transpose<<<dim3(3072/32, 1024/32), tb, 0, stream>>>(Wqkv + (size_t)l*1024*3072, wt, 1024, 3072);
    k_gemm<0><<<dim3(94, 24), 256, 0, stream>>>(xb, wt, Mz, 3072, 1024, bqkv + l*3072, nullptr, qB);
    // attention
    k_attn<<<dim3(6, 256), 256, 0, stream>>>(qB, kB, vB, oB);
    // Wo + residual
    k_transpose<<<dim3(1024/32, 1024/32), tb, 0, stream>>>(Wo + (size_t)l*1024*1024, wt, 1024, 1024);
    k_gemm<1><<<dim3(94, 8), 256, 0, stream>>>(oB, wt, Mz, 1024, 1024, bo + l*1024, x, nullptr);
    k_ln<<<Mz, 256, 0, stream>>>(x, xb, ln1g + l*1024, ln1b + l*1024);
    // FFN
    k_transpose<<<dim3(4096/32, 1024/32), tb, 0, stream>>>(W1 + (size_t)l*1024*4096, wt, 1024, 4096);
    k_gemm<2><<<dim3(94, 32), 256, 0, stream>>>(xb, wt, Mz, 4096, 1024, b1 + l*4096, nullptr, hB);
    k_transpose<<<dim3(1024/32, 4096/32), tb, 0, stream>>>(W2 + (size_t)l*4096*1024, wt, 4096, 1024);
    k_gemm<1><<<dim3(94, 8), 256, 0, stream>>>(hB, wt, Mz, 1024, 4096, b2 + l*1024, x, nullptr);
    k_ln<<<Mz, 256, 0, stream>>>(x, xb, ln2g + l*1024, ln2b + l*1024);
  }
  k_out<<<4000, 64, 0, stream>>>(x, postW, postb, out);
}